// Round 17
// baseline (136.133 us; speedup 1.0000x reference)
//
#include <hip/hip_runtime.h>
#include <hip/hip_bf16.h>

// MultiHeadAttention: B=4 H=12 S=2048 D=64 E=768, causal. fp32 in/out, bf16 MFMA compute.
// R16: best config (R15) + v-epilogue via LDS (coalesced dwordx4 stores instead of
//      4B scatter) + launch_bounds(128,4) on both GEMMs. All else identical.

typedef __attribute__((ext_vector_type(8))) short bf16x8;
typedef __attribute__((ext_vector_type(4))) float f32x4;
typedef __attribute__((ext_vector_type(16))) float f32x16;
typedef __attribute__((ext_vector_type(4))) uint u32x4;

// ws offsets in bf16 elements
#define OFF_XB   0            // 8192*768            = 6291456
#define OFF_WT   6291456      // 3 * 12*64*768       = 1769472
#define OFF_WPT  8060928      // 768*768             =  589824
#define OFF_QKV  8650752      // q,k: 2 * 6291456; then vt (uints)
#define OFF_AO   27525120     // 8192*768            = 6291456

#define SCALE_LOG2E 0.1803368801111204f   // (1/8) * log2(e)

__device__ inline ushort f2bf(float f) {
  __hip_bfloat16 h = __float2bfloat16(f);
  return *reinterpret_cast<ushort*>(&h);
}
__device__ inline uint cvt_pk(float lo, float hi) {
  uint r;
  asm("v_cvt_pk_bf16_f32 %0, %1, %2" : "=v"(r) : "v"(lo), "v"(hi));
  return r;
}
#define GLOAD16(g, l)                                                              \
  __builtin_amdgcn_global_load_lds(                                                \
      (const __attribute__((address_space(1))) uint*)(g),                          \
      (__attribute__((address_space(3))) uint*)(l), 16, 0, 0)

#define WAITBAR(n) asm volatile("s_waitcnt vmcnt(" #n ")\ns_barrier" ::: "memory")
#define ENDBAR()   asm volatile("s_waitcnt lgkmcnt(0)\ns_barrier" ::: "memory")
#define LGKM0()    asm volatile("s_waitcnt lgkmcnt(0)" ::: "memory")
#define SCHED0()   __builtin_amdgcn_sched_barrier(0)

// ---------- fused prep: blocks [0,3072) cvt x->bf16; [3072,3504) Wq/Wk/Wv transpose;
// [3504,3648) Wp transpose. 256 threads.
__global__ __launch_bounds__(256) void prep(const float* __restrict__ x,
                                            const float* __restrict__ Wq,
                                            const float* __restrict__ Wk,
                                            const float* __restrict__ Wv,
                                            const float* __restrict__ Wp,
                                            ushort* __restrict__ xb,
                                            ushort* __restrict__ wt,
                                            ushort* __restrict__ wpt) {
  __shared__ ushort tile[64][130];
  int bx = blockIdx.x;
  int t = threadIdx.x;
  if (bx < 3072) {
    int i = bx * 256 + t;
    float4 a = *(const float4*)&x[(size_t)i * 8];
    float4 b = *(const float4*)&x[(size_t)i * 8 + 4];
    u32x4 pk = {cvt_pk(a.x, a.y), cvt_pk(a.z, a.w), cvt_pk(b.x, b.y), cvt_pk(b.z, b.w)};
    *(bf16x8*)&xb[(size_t)i * 8] = __builtin_bit_cast(bf16x8, pk);
    return;
  }
  if (bx < 3504) {
    int local = bx - 3072;
    int mat = local / 12, te = local % 12;
    const float* src = (mat < 12) ? Wq : (mat < 24) ? Wk : Wv;
    int m12 = mat % 12;
    size_t base = (size_t)m12 * 768 * 64;
#pragma unroll
    for (int i = 0; i < 16; i++) {
      int idx = i * 256 + t;
      int r = idx >> 6, c = idx & 63;
      tile[r][c] = f2bf(src[base + (size_t)(te * 64 + r) * 64 + c]);
    }
    __syncthreads();
    size_t obase = (size_t)mat * 49152;
#pragma unroll
    for (int i = 0; i < 16; i++) {
      int idx = i * 256 + t;
      int c = idx >> 6, r = idx & 63;
      wt[obase + (size_t)c * 768 + te * 64 + r] = tile[r][c];
    }
    return;
  }
  {
    int idx0 = bx - 3504;
    int te = idx0 / 12, td = idx0 % 12;
#pragma unroll
    for (int i = 0; i < 16; i++) {
      int idx = i * 256 + t;
      int r = idx >> 6, c = idx & 63;
      tile[r][c] = f2bf(Wp[(size_t)(te * 64 + r) * 768 + td * 64 + c]);
    }
    __syncthreads();
#pragma unroll
    for (int i = 0; i < 16; i++) {
      int idx = i * 256 + t;
      int c = idx >> 6, r = idx & 63;
      wpt[(size_t)(td * 64 + c) * 768 + te * 64 + r] = tile[r][c];
    }
  }
}

// swizzle term for row (row multiple-of-16 bases drop out): ((row + (row>>2)) & 3)
__device__ inline uint swz(uint row) { return (row + (row >> 2)) & 3; }

// ---------- QKV GEMM (R8 form + LDS v-epilogue): xb[8192,768] @ Wt -> q,k,vt
// grid (64, 18), 128 thr = 2 waves; wave w owns rows w*64, all 128 cols.
__global__ __launch_bounds__(128, 4) void gemm_qkv(const ushort* __restrict__ X,
                                                   const ushort* __restrict__ Wt,
                                                   ushort* __restrict__ qkv,
                                                   uint* __restrict__ vtg) {
  __shared__ ushort Ash[2][128 * 32];
  __shared__ ushort Bsh[2][128 * 32];
  int mb = blockIdx.x, nb = blockIdx.y;
  int t = threadIdx.x, w = t >> 6, lane = t & 63, lo = lane & 15, g = lane >> 4;
  const ushort* Ab = X + (size_t)mb * 128 * 768;
  const ushort* Bb = Wt + (size_t)nb * 128 * 768;
  f32x4 acc[4][8];
#pragma unroll
  for (int fi = 0; fi < 4; fi++)
#pragma unroll
    for (int fj = 0; fj < 8; fj++) acc[fi][fj] = (f32x4){0.f, 0.f, 0.f, 0.f};
  uint srow[4], ssc[4];
#pragma unroll
  for (int j = 0; j < 4; j++) {
    uint ci = j * 128 + t;
    srow[j] = ci >> 2;
    ssc[j] = ((ci & 3) ^ swz(ci >> 2)) << 4;
  }

#define QKV_STAGE(tile, bsel)                                                         \
  {                                                                                   \
    int e0 = (tile) * 32;                                                             \
    _Pragma("unroll")                                                                 \
    for (int j = 0; j < 4; j++) {                                                     \
      GLOAD16((const char*)(Ab + (size_t)srow[j] * 768 + e0) + ssc[j],                \
              &Ash[bsel][(j * 128 + w * 64) * 8]);                                    \
      GLOAD16((const char*)(Bb + (size_t)srow[j] * 768 + e0) + ssc[j],                \
              &Bsh[bsel][(j * 128 + w * 64) * 8]);                                    \
    }                                                                                 \
  }

  QKV_STAGE(0, 0);
  QKV_STAGE(1, 1);
  uint rsw = swz(lo) << 4;
  for (int it = 0; it < 24; ++it) {
    if (it < 23) { WAITBAR(8); } else { WAITBAR(0); }
    const ushort* Acur = Ash[it & 1];
    const ushort* Bcur = Bsh[it & 1];
    bf16x8 af[4], bf[8];
#pragma unroll
    for (int fi = 0; fi < 4; fi++) {
      int arow = w * 64 + fi * 16 + lo;
      af[fi] = *(const bf16x8*)((const char*)Acur + arow * 64 + ((g << 4) ^ rsw));
    }
#pragma unroll
    for (int fj = 0; fj < 8; fj++) {
      int brow = fj * 16 + lo;
      bf[fj] = *(const bf16x8*)((const char*)Bcur + brow * 64 + ((g << 4) ^ rsw));
    }
#pragma unroll
    for (int fi = 0; fi < 4; fi++)
#pragma unroll
      for (int fj = 0; fj < 8; fj++)
        acc[fi][fj] = __builtin_amdgcn_mfma_f32_16x16x32_bf16(af[fi], bf[fj], acc[fi][fj], 0, 0, 0);
    if (it < 22) {
      ENDBAR();
      QKV_STAGE(it + 2, it & 1);
    }
  }
#undef QKV_STAGE
  __syncthreads();   // K-loop LDS reads done in all waves; reuse LDS for epilogue
  // wave-private LDS staging region for v (needs 64*33 uints = 8448B <= 16KB per array)
  uint* Vl = (uint*)(w ? (void*)&Bsh[0][0] : (void*)&Ash[0][0]);
#pragma unroll
  for (int half = 0; half < 2; half++) {
    int mat = nb * 2 + half;  // 0..35
    int ty = mat / 12, h = mat % 12;
    if (ty < 2) {
      // q/k: direct stores (32B quarter-wave segments)
#pragma unroll
      for (int fj4 = 0; fj4 < 4; fj4++) {
        int fj = half * 4 + fj4;
        int d = fj4 * 16 + lo;
#pragma unroll
        for (int fi = 0; fi < 4; fi++)
#pragma unroll
          for (int rr = 0; rr < 4; rr++) {
            int m = mb * 128 + w * 64 + fi * 16 + g * 4 + rr;
            int b = m >> 11, s = m & 2047;
            qkv[(size_t)ty * 6291456 + (size_t)(b * 12 + h) * 131072 + (size_t)s * 64 + d] =
                f2bf(acc[fi][fj][rr]);
          }
      }
    } else {
      // v: stage [d][pr] uints in LDS (stride 33, conflict-free), then coalesced stores
#pragma unroll
      for (int fj4 = 0; fj4 < 4; fj4++) {
        int fj = half * 4 + fj4;
        int d = fj4 * 16 + lo;
#pragma unroll
        for (int fi = 0; fi < 4; fi++)
#pragma unroll
          for (int rr = 0; rr < 4; rr += 2) {
            uint pk = cvt_pk(acc[fi][fj][rr], acc[fi][fj][rr + 1]);
            Vl[d * 33 + fi * 8 + g * 2 + (rr >> 1)] = pk;
          }
      }
      LGKM0(); SCHED0();   // same-wave LDS RAW fence (rule #18)
      // wave's v region = 2048 contiguous uints at vtg[(b*12+h)*65536 + stile*2048]
      int b = mb >> 4;
      int stile = (mb & 15) * 2 + w;
      uint* dst = vtg + (size_t)(b * 12 + h) * 65536 + stile * 2048;
#pragma unroll
      for (int p = 0; p < 8; p++) {
        int li = p * 256 + lane * 4;       // 4 consecutive uints
        int d = li >> 5, pr = li & 31;
        u32x4 v4 = *(const u32x4*)&Vl[d * 33 + pr];
        *(u32x4*)&dst[li] = v4;
      }
    }
  }
}

// ---------- causal flash attention (R5 form, best measured): fixed-max softmax,
// l via MFMA(ones), reg-staged dbuf K/V (padded LDS, zero conflicts).
// grid: x = 768: head = x%48 (-> XCD x%8), qb = 15 - x/48 (heavy first).
__global__ __launch_bounds__(256, 3) void attn_fwd(const ushort* __restrict__ Qg,
                                                   const ushort* __restrict__ Kg,
                                                   const uint* __restrict__ Vtg,
                                                   ushort* __restrict__ ao) {
  __shared__ ushort Ksh[2][64 * 72];
  __shared__ uint Vsh[2][64 * 36];
  int x = blockIdx.x;
  int head = x % 48;
  int qb = 15 - x / 48;
  int T = 2 * qb + 2;
  int t = threadIdx.x, w = t >> 6, q31 = t & 31, hi = (t & 63) >> 5;
  const ushort* Q = Qg + (size_t)head * 131072;
  const ushort* K = Kg + (size_t)head * 131072;
  const uint* V = Vtg + (size_t)head * 65536;
  int qstart = qb * 128 + 32 * w;
  int qg = qstart + q31;
  bf16x8 qf[4];
#pragma unroll
  for (int s = 0; s < 4; s++)
    qf[s] = *(const bf16x8*)&Q[(size_t)qg * 64 + s * 16 + hi * 8];
  bf16x8 ones;
#pragma unroll
  for (int i = 0; i < 8; i++) ones[i] = (short)0x3F80;
  f32x16 oacc[2], lacc;
#pragma unroll
  for (int r = 0; r < 16; r++) { oacc[0][r] = 0.f; oacc[1][r] = 0.f; lacc[r] = 0.f; }
  int sr = t >> 3, sc = t & 7;
  bf16x8 kreg[2];
  u32x4 vreg[2];
#pragma unroll
  for (int i = 0; i < 2; i++) {
    kreg[i] = *(const bf16x8*)&K[(size_t)(i * 32 + sr) * 64 + sc * 8];
    vreg[i] = *(const u32x4*)&V[(i * 32 + sr) * 32 + sc * 4];
  }
#pragma unroll
  for (int i = 0; i < 2; i++) {
    *(bf16x8*)&Ksh[0][(i * 32 + sr) * 72 + sc * 8] = kreg[i];
    *(u32x4*)&Vsh[0][(i * 32 + sr) * 36 + sc * 4] = vreg[i];
  }
  for (int kb = 0; kb < T; kb++) {
    __syncthreads();
    if (kb + 1 < T) {
      int t1 = (kb + 1) * 64;
#pragma unroll
      for (int i = 0; i < 2; i++) {
        kreg[i] = *(const bf16x8*)&K[(size_t)(t1 + i * 32 + sr) * 64 + sc * 8];
        vreg[i] = *(const u32x4*)&V[(kb + 1) * 2048 + (i * 32 + sr) * 32 + sc * 4];
      }
    }
    int t0 = kb * 64;
    if (t0 <= qstart + 31) {
      const ushort* Kb = Ksh[kb & 1];
      const uint* Vb = Vsh[kb & 1];
      bool act1 = (t0 + 32 <= qstart + 31);
      f32x16 st0, st1;
#pragma unroll
      for (int r = 0; r < 16; r++) { st0[r] = 0.f; st1[r] = 0.f; }
#pragma unroll
      for (int s = 0; s < 4; s++) {
        bf16x8 kf = *(const bf16x8*)&Kb[q31 * 72 + s * 16 + hi * 8];
        st0 = __builtin_amdgcn_mfma_f32_32x32x16_bf16(kf, qf[s], st0, 0, 0, 0);
      }
      if (act1) {
#pragma unroll
        for (int s = 0; s < 4; s++) {
          bf16x8 kf = *(const bf16x8*)&Kb[(32 + q31) * 72 + s * 16 + hi * 8];
          st1 = __builtin_amdgcn_mfma_f32_32x32x16_bf16(kf, qf[s], st1, 0, 0, 0);
        }
      }
      if (t0 + 31 > qstart) {
        int base = t0 - qstart;
#pragma unroll
        for (int r = 0; r < 16; r++) {
          int crow = (r & 3) + 8 * (r >> 2) + 4 * hi;
          if (base + crow > q31) st0[r] = -3e38f;
        }
      }
      if (act1 && (t0 + 63 > qstart)) {
        int base = t0 + 32 - qstart;
#pragma unroll
        for (int r = 0; r < 16; r++) {
          int crow = (r & 3) + 8 * (r >> 2) + 4 * hi;
          if (base + crow > q31) st1[r] = -3e38f;
        }
      }
#pragma unroll
      for (int r = 0; r < 16; r++)
        st0[r] = __builtin_amdgcn_exp2f(st0[r] * SCALE_LOG2E);
      if (act1) {
#pragma unroll
        for (int r = 0; r < 16; r++)
          st1[r] = __builtin_amdgcn_exp2f(st1[r] * SCALE_LOG2E);
      }
      int ns = act1 ? 4 : 2;
      bf16x8 paf[4];
#pragma unroll
      for (int s = 0; s < 4; s++) {
        if (s < ns) {
          const f32x16& sv = (s < 2) ? st0 : st1;
          int rb = (s & 1) * 8;
          uint a = cvt_pk(sv[rb + 0], sv[rb + 1]);
          uint b2 = cvt_pk(sv[rb + 2], sv[rb + 3]);
          uint c = cvt_pk(sv[rb + 4], sv[rb + 5]);
          uint d = cvt_pk(sv[rb + 6], sv[rb + 7]);
          asm volatile("v_permlane32_swap_b32 %0, %1" : "+v"(a), "+v"(c));
          asm volatile("v_permlane32_swap_b32 %0, %1" : "+v"(b2), "+v"(d));
          u32x4 u4 = {a, b2, c, d};
          paf[s] = __builtin_bit_cast(bf16x8, u4);
        }
      }
#pragma unroll
      for (int s = 0; s < 4; s++) {
        if (s < ns) {
          lacc = __builtin_amdgcn_mfma_f32_32x32x16_bf16(paf[s], ones, lacc, 0, 0, 0);
#pragma unroll
          for (int dt = 0; dt < 2; dt++) {
            bf16x8 vf = *(const bf16x8*)&Vb[(dt * 32 + q31) * 36 + s * 8 + hi * 4];
            oacc[dt] = __builtin_amdgcn_mfma_f32_32x32x16_bf16(paf[s], vf, oacc[dt], 0, 0, 0);
          }
        }
      }
    }
    if (kb + 1 < T) {
      int b2 = (kb + 1) & 1;
#pragma unroll
      for (int i = 0; i < 2; i++) {
        *(bf16x8*)&Ksh[b2][(i * 32 + sr) * 72 + sc * 8] = kreg[i];
        *(u32x4*)&Vsh[b2][(i * 32 + sr) * 36 + sc * 4] = vreg[i];
      }
    }
  }
  int hh = head % 12, bb = head / 12;
#pragma unroll
  for (int dt = 0; dt < 2; dt++)
#pragma unroll
    for (int r = 0; r < 16; r++) {
      int qr = qstart + (r & 3) + 8 * (r >> 2) + 4 * hi;
      ao[(size_t)(bb * 2048 + qr) * 768 + hh * 64 + dt * 32 + q31] =
          f2bf(oacc[dt][r] / lacc[r]);
    }
}

// ---------- output projection (R8 form): ao[8192,768] @ Wpt + bp -> out fp32.
// grid (64, 6), 128 thr = 2 waves; depth-2 counted-vmcnt dbuf.
__global__ __launch_bounds__(128, 4) void gemm_out(const ushort* __restrict__ A,
                                                   const ushort* __restrict__ Bt,
                                                   const float* __restrict__ bias,
                                                   float* __restrict__ out) {
  __shared__ ushort Ash[2][128 * 32];
  __shared__ ushort Bsh[2][128 * 32];
  int mb = blockIdx.x, nb = blockIdx.y;
  int t = threadIdx.x, w = t >> 6, lane = t & 63, lo = lane & 15, g = lane >> 4;
  const ushort* Ab = A + (size_t)mb * 128 * 768;
  const ushort* Bb = Bt + (size_t)nb * 128 * 768;
  f32x4 acc[4][8];
#pragma unroll
  for (int fi = 0; fi < 4; fi++)
#pragma unroll
    for (int fj = 0; fj < 8; fj++) acc[fi][fj] = (f32x4){0.f, 0.f, 0.f, 0.f};
  uint srow[4], ssc[4];
#pragma unroll
  for (int j = 0; j < 4; j++) {
    uint ci = j * 128 + t;
    srow[j] = ci >> 2;
    ssc[j] = ((ci & 3) ^ swz(ci >> 2)) << 4;
  }

#define OUT_STAGE(tile, bsel)                                                         \
  {                                                                                   \
    int e0 = (tile) * 32;                                                             \
    _Pragma("unroll")                                                                 \
    for (int j = 0; j < 4; j++) {                                                     \
      GLOAD16((const char*)(Ab + (size_t)srow[j] * 768 + e0) + ssc[j],                \
              &Ash[bsel][(j * 128 + w * 64) * 8]);                                    \
      GLOAD16((const char*)(Bb + (size_t)srow[j] * 768 + e0) + ssc[j],                \
              &Bsh[bsel][(j * 128 + w * 64) * 8]);                                    \
    }                                                                                 \
  }

  OUT_STAGE(0, 0);
  OUT_STAGE(1, 1);
  uint rsw = swz(lo) << 4;
  for (int it = 0; it < 24; ++it) {
    if (it < 23) { WAITBAR(8); } else { WAITBAR(0); }
    const ushort* Acur = Ash[it & 1];
    const ushort* Bcur = Bsh[it & 1];
    bf16x8 af[4], bf[8];
#pragma unroll
    for (int fi = 0; fi < 4; fi++) {
      int arow = w * 64 + fi * 16 + lo;
      af[fi] = *(const bf16x8*)((const char*)Acur + arow * 64 + ((g << 4) ^ rsw));
    }
#pragma unroll
    for (int fj = 0; fj < 8; fj++) {
      int brow = fj * 16 + lo;
      bf[fj] = *(const bf16x8*)((const char*)Bcur + brow * 64 + ((g << 4) ^ rsw));
    }
#pragma unroll
    for (int fi = 0; fi < 4; fi++)
#pragma unroll
      for (int fj = 0; fj < 8; fj++)
        acc[fi][fj] = __builtin_amdgcn_mfma_f32_16x16x32_bf16(af[fi], bf[fj], acc[fi][fj], 0, 0, 0);
    if (it < 22) {
      ENDBAR();
      OUT_STAGE(it + 2, it & 1);
    }
  }
#undef OUT_STAGE
#pragma unroll
  for (int fj = 0; fj < 8; fj++) {
    int col = nb * 128 + fj * 16 + lo;
    float bv = bias[col];
#pragma unroll
    for (int fi = 0; fi < 4; fi++)
#pragma unroll
      for (int rr = 0; rr < 4; rr++) {
        int m = mb * 128 + w * 64 + fi * 16 + g * 4 + rr;
        out[(size_t)m * 768 + col] = acc[fi][fj][rr] + bv;
      }
  }
}

extern "C" void kernel_launch(void* const* d_in, const int* in_sizes, int n_in,
                              void* d_out, int out_size, void* d_ws, size_t ws_size,
                              hipStream_t stream) {
  const float* x  = (const float*)d_in[0];
  const float* Wq = (const float*)d_in[1];
  const float* Wk = (const float*)d_in[2];
  const float* Wv = (const float*)d_in[3];
  const float* Wp = (const float*)d_in[4];
  const float* bp = (const float*)d_in[5];
  float* out = (float*)d_out;
  ushort* ws = (ushort*)d_ws;

  ushort* xb  = ws + OFF_XB;
  ushort* wt  = ws + OFF_WT;
  ushort* wpt = ws + OFF_WPT;
  ushort* qkv = ws + OFF_QKV;                          // q, k
  uint*   vt  = (uint*)(ws + OFF_QKV + 2 * 6291456);   // packed-transposed v
  ushort* ao  = ws + OFF_AO;

  prep<<<dim3(3648), 256, 0, stream>>>(x, Wq, Wk, Wv, Wp, xb, wt, wpt);
  gemm_qkv<<<dim3(64, 18), 128, 0, stream>>>(xb, wt, qkv, vt);
  attn_fwd<<<dim3(768), 256, 0, stream>>>(qkv, qkv + 6291456, vt, ao);
  gemm_out<<<dim3(64, 6), 128, 0, stream>>>(ao, wpt, bp, out);
}

// Round 18
// 126.369 us; speedup vs baseline: 1.0773x; 1.0773x over previous
//
#include <hip/hip_runtime.h>
#include <hip/hip_bf16.h>

// MultiHeadAttention: B=4 H=12 S=2048 D=64 E=768, causal. fp32 in/out, bf16 MFMA compute.
// R17: exact revert to R15 (best measured, 126.4us): fused prep + R8 2-phase GEMMs +
//      R5 reg-staged attn. R16's v-epilogue/launch-bounds deltas removed (regressed).

typedef __attribute__((ext_vector_type(8))) short bf16x8;
typedef __attribute__((ext_vector_type(4))) float f32x4;
typedef __attribute__((ext_vector_type(16))) float f32x16;
typedef __attribute__((ext_vector_type(4))) uint u32x4;

// ws offsets in bf16 elements
#define OFF_XB   0            // 8192*768            = 6291456
#define OFF_WT   6291456      // 3 * 12*64*768       = 1769472
#define OFF_WPT  8060928      // 768*768             =  589824
#define OFF_QKV  8650752      // q,k: 2 * 6291456; then vt (uints)
#define OFF_AO   27525120     // 8192*768            = 6291456

#define SCALE_LOG2E 0.1803368801111204f   // (1/8) * log2(e)

__device__ inline ushort f2bf(float f) {
  __hip_bfloat16 h = __float2bfloat16(f);
  return *reinterpret_cast<ushort*>(&h);
}
__device__ inline uint cvt_pk(float lo, float hi) {
  uint r;
  asm("v_cvt_pk_bf16_f32 %0, %1, %2" : "=v"(r) : "v"(lo), "v"(hi));
  return r;
}
#define GLOAD16(g, l)                                                              \
  __builtin_amdgcn_global_load_lds(                                                \
      (const __attribute__((address_space(1))) uint*)(g),                          \
      (__attribute__((address_space(3))) uint*)(l), 16, 0, 0)

#define WAITBAR(n) asm volatile("s_waitcnt vmcnt(" #n ")\ns_barrier" ::: "memory")
#define ENDBAR()   asm volatile("s_waitcnt lgkmcnt(0)\ns_barrier" ::: "memory")

// ---------- fused prep: blocks [0,3072) cvt x->bf16; [3072,3504) Wq/Wk/Wv transpose;
// [3504,3648) Wp transpose. 256 threads.
__global__ __launch_bounds__(256) void prep(const float* __restrict__ x,
                                            const float* __restrict__ Wq,
                                            const float* __restrict__ Wk,
                                            const float* __restrict__ Wv,
                                            const float* __restrict__ Wp,
                                            ushort* __restrict__ xb,
                                            ushort* __restrict__ wt,
                                            ushort* __restrict__ wpt) {
  __shared__ ushort tile[64][130];
  int bx = blockIdx.x;
  int t = threadIdx.x;
  if (bx < 3072) {
    // cvt: 8 elems/thread
    int i = bx * 256 + t;
    float4 a = *(const float4*)&x[(size_t)i * 8];
    float4 b = *(const float4*)&x[(size_t)i * 8 + 4];
    u32x4 pk = {cvt_pk(a.x, a.y), cvt_pk(a.z, a.w), cvt_pk(b.x, b.y), cvt_pk(b.z, b.w)};
    *(bf16x8*)&xb[(size_t)i * 8] = __builtin_bit_cast(bf16x8, pk);
    return;
  }
  if (bx < 3504) {
    // Wq/Wk/Wv 64x64 transpose+convert; local = mat*12 + te
    int local = bx - 3072;
    int mat = local / 12, te = local % 12;
    const float* src = (mat < 12) ? Wq : (mat < 24) ? Wk : Wv;
    int m12 = mat % 12;
    size_t base = (size_t)m12 * 768 * 64;
#pragma unroll
    for (int i = 0; i < 16; i++) {
      int idx = i * 256 + t;
      int r = idx >> 6, c = idx & 63;
      tile[r][c] = f2bf(src[base + (size_t)(te * 64 + r) * 64 + c]);
    }
    __syncthreads();
    size_t obase = (size_t)mat * 49152;
#pragma unroll
    for (int i = 0; i < 16; i++) {
      int idx = i * 256 + t;
      int c = idx >> 6, r = idx & 63;
      wt[obase + (size_t)c * 768 + te * 64 + r] = tile[r][c];
    }
    return;
  }
  {
    // Wp 768x768 transpose+convert; idx = te*12 + td
    int idx0 = bx - 3504;
    int te = idx0 / 12, td = idx0 % 12;
#pragma unroll
    for (int i = 0; i < 16; i++) {
      int idx = i * 256 + t;
      int r = idx >> 6, c = idx & 63;
      tile[r][c] = f2bf(Wp[(size_t)(te * 64 + r) * 768 + td * 64 + c]);
    }
    __syncthreads();
#pragma unroll
    for (int i = 0; i < 16; i++) {
      int idx = i * 256 + t;
      int c = idx >> 6, r = idx & 63;
      wpt[(size_t)(td * 64 + c) * 768 + te * 64 + r] = tile[r][c];
    }
  }
}

// swizzle term for row (row multiple-of-16 bases drop out): ((row + (row>>2)) & 3)
__device__ inline uint swz(uint row) { return (row + (row >> 2)) & 3; }

// ---------- QKV GEMM (R8 form, 53.5us proven): xb[8192,768] @ Wt -> q,k,vt
// grid (64, 18), 128 thr = 2 waves; wave w owns rows w*64, all 128 cols.
__global__ __launch_bounds__(128, 2) void gemm_qkv(const ushort* __restrict__ X,
                                                   const ushort* __restrict__ Wt,
                                                   ushort* __restrict__ qkv,
                                                   uint* __restrict__ vtg) {
  __shared__ ushort Ash[2][128 * 32];
  __shared__ ushort Bsh[2][128 * 32];
  int mb = blockIdx.x, nb = blockIdx.y;
  int t = threadIdx.x, w = t >> 6, lane = t & 63, lo = lane & 15, g = lane >> 4;
  const ushort* Ab = X + (size_t)mb * 128 * 768;
  const ushort* Bb = Wt + (size_t)nb * 128 * 768;
  f32x4 acc[4][8];
#pragma unroll
  for (int fi = 0; fi < 4; fi++)
#pragma unroll
    for (int fj = 0; fj < 8; fj++) acc[fi][fj] = (f32x4){0.f, 0.f, 0.f, 0.f};
  uint srow[4], ssc[4];
#pragma unroll
  for (int j = 0; j < 4; j++) {
    uint ci = j * 128 + t;
    srow[j] = ci >> 2;
    ssc[j] = ((ci & 3) ^ swz(ci >> 2)) << 4;
  }

#define QKV_STAGE(tile, bsel)                                                         \
  {                                                                                   \
    int e0 = (tile) * 32;                                                             \
    _Pragma("unroll")                                                                 \
    for (int j = 0; j < 4; j++) {                                                     \
      GLOAD16((const char*)(Ab + (size_t)srow[j] * 768 + e0) + ssc[j],                \
              &Ash[bsel][(j * 128 + w * 64) * 8]);                                    \
      GLOAD16((const char*)(Bb + (size_t)srow[j] * 768 + e0) + ssc[j],                \
              &Bsh[bsel][(j * 128 + w * 64) * 8]);                                    \
    }                                                                                 \
  }

  QKV_STAGE(0, 0);
  QKV_STAGE(1, 1);
  uint rsw = swz(lo) << 4;
  for (int it = 0; it < 24; ++it) {
    if (it < 23) { WAITBAR(8); } else { WAITBAR(0); }
    const ushort* Acur = Ash[it & 1];
    const ushort* Bcur = Bsh[it & 1];
    bf16x8 af[4], bf[8];
#pragma unroll
    for (int fi = 0; fi < 4; fi++) {
      int arow = w * 64 + fi * 16 + lo;
      af[fi] = *(const bf16x8*)((const char*)Acur + arow * 64 + ((g << 4) ^ rsw));
    }
#pragma unroll
    for (int fj = 0; fj < 8; fj++) {
      int brow = fj * 16 + lo;
      bf[fj] = *(const bf16x8*)((const char*)Bcur + brow * 64 + ((g << 4) ^ rsw));
    }
#pragma unroll
    for (int fi = 0; fi < 4; fi++)
#pragma unroll
      for (int fj = 0; fj < 8; fj++)
        acc[fi][fj] = __builtin_amdgcn_mfma_f32_16x16x32_bf16(af[fi], bf[fj], acc[fi][fj], 0, 0, 0);
    if (it < 22) {
      ENDBAR();
      QKV_STAGE(it + 2, it & 1);
    }
  }
#undef QKV_STAGE
#pragma unroll
  for (int fj = 0; fj < 8; fj++) {
    int mat = nb * 2 + (fj >> 2);  // 0..35
    int ty = mat / 12, h = mat % 12;
    int d = (fj & 3) * 16 + lo;
    if (ty < 2) {
#pragma unroll
      for (int fi = 0; fi < 4; fi++)
#pragma unroll
        for (int rr = 0; rr < 4; rr++) {
          int m = mb * 128 + w * 64 + fi * 16 + g * 4 + rr;
          int b = m >> 11, s = m & 2047;
          qkv[(size_t)ty * 6291456 + (size_t)(b * 12 + h) * 131072 + (size_t)s * 64 + d] =
              f2bf(acc[fi][fj][rr]);
        }
    } else {
      // v: transposed pair-packed per head: [32 tiles][64 d][32 kv-pairs] uints
#pragma unroll
      for (int fi = 0; fi < 4; fi++)
#pragma unroll
        for (int rr = 0; rr < 4; rr += 2) {
          int m = mb * 128 + w * 64 + fi * 16 + g * 4 + rr;
          int b = m >> 11, s = m & 2047;
          uint pk = cvt_pk(acc[fi][fj][rr], acc[fi][fj][rr + 1]);
          vtg[(size_t)(b * 12 + h) * 65536 + (s >> 6) * 2048 + d * 32 + ((s & 63) >> 1)] = pk;
        }
    }
  }
}

// ---------- causal flash attention (R5 form, best measured): fixed-max softmax,
// l via MFMA(ones), reg-staged dbuf K/V (padded LDS, zero conflicts).
// grid: x = 768: head = x%48 (-> XCD x%8), qb = 15 - x/48 (heavy first).
__global__ __launch_bounds__(256, 3) void attn_fwd(const ushort* __restrict__ Qg,
                                                   const ushort* __restrict__ Kg,
                                                   const uint* __restrict__ Vtg,
                                                   ushort* __restrict__ ao) {
  __shared__ ushort Ksh[2][64 * 72];
  __shared__ uint Vsh[2][64 * 36];
  int x = blockIdx.x;
  int head = x % 48;
  int qb = 15 - x / 48;
  int T = 2 * qb + 2;
  int t = threadIdx.x, w = t >> 6, q31 = t & 31, hi = (t & 63) >> 5;
  const ushort* Q = Qg + (size_t)head * 131072;
  const ushort* K = Kg + (size_t)head * 131072;
  const uint* V = Vtg + (size_t)head * 65536;
  int qstart = qb * 128 + 32 * w;
  int qg = qstart + q31;
  bf16x8 qf[4];
#pragma unroll
  for (int s = 0; s < 4; s++)
    qf[s] = *(const bf16x8*)&Q[(size_t)qg * 64 + s * 16 + hi * 8];
  bf16x8 ones;
#pragma unroll
  for (int i = 0; i < 8; i++) ones[i] = (short)0x3F80;
  f32x16 oacc[2], lacc;
#pragma unroll
  for (int r = 0; r < 16; r++) { oacc[0][r] = 0.f; oacc[1][r] = 0.f; lacc[r] = 0.f; }
  int sr = t >> 3, sc = t & 7;
  bf16x8 kreg[2];
  u32x4 vreg[2];
#pragma unroll
  for (int i = 0; i < 2; i++) {
    kreg[i] = *(const bf16x8*)&K[(size_t)(i * 32 + sr) * 64 + sc * 8];
    vreg[i] = *(const u32x4*)&V[(i * 32 + sr) * 32 + sc * 4];
  }
#pragma unroll
  for (int i = 0; i < 2; i++) {
    *(bf16x8*)&Ksh[0][(i * 32 + sr) * 72 + sc * 8] = kreg[i];
    *(u32x4*)&Vsh[0][(i * 32 + sr) * 36 + sc * 4] = vreg[i];
  }
  for (int kb = 0; kb < T; kb++) {
    __syncthreads();
    if (kb + 1 < T) {
      int t1 = (kb + 1) * 64;
#pragma unroll
      for (int i = 0; i < 2; i++) {
        kreg[i] = *(const bf16x8*)&K[(size_t)(t1 + i * 32 + sr) * 64 + sc * 8];
        vreg[i] = *(const u32x4*)&V[(kb + 1) * 2048 + (i * 32 + sr) * 32 + sc * 4];
      }
    }
    int t0 = kb * 64;
    if (t0 <= qstart + 31) {
      const ushort* Kb = Ksh[kb & 1];
      const uint* Vb = Vsh[kb & 1];
      bool act1 = (t0 + 32 <= qstart + 31);
      f32x16 st0, st1;
#pragma unroll
      for (int r = 0; r < 16; r++) { st0[r] = 0.f; st1[r] = 0.f; }
#pragma unroll
      for (int s = 0; s < 4; s++) {
        bf16x8 kf = *(const bf16x8*)&Kb[q31 * 72 + s * 16 + hi * 8];
        st0 = __builtin_amdgcn_mfma_f32_32x32x16_bf16(kf, qf[s], st0, 0, 0, 0);
      }
      if (act1) {
#pragma unroll
        for (int s = 0; s < 4; s++) {
          bf16x8 kf = *(const bf16x8*)&Kb[(32 + q31) * 72 + s * 16 + hi * 8];
          st1 = __builtin_amdgcn_mfma_f32_32x32x16_bf16(kf, qf[s], st1, 0, 0, 0);
        }
      }
      if (t0 + 31 > qstart) {
        int base = t0 - qstart;
#pragma unroll
        for (int r = 0; r < 16; r++) {
          int crow = (r & 3) + 8 * (r >> 2) + 4 * hi;
          if (base + crow > q31) st0[r] = -3e38f;
        }
      }
      if (act1 && (t0 + 63 > qstart)) {
        int base = t0 + 32 - qstart;
#pragma unroll
        for (int r = 0; r < 16; r++) {
          int crow = (r & 3) + 8 * (r >> 2) + 4 * hi;
          if (base + crow > q31) st1[r] = -3e38f;
        }
      }
#pragma unroll
      for (int r = 0; r < 16; r++)
        st0[r] = __builtin_amdgcn_exp2f(st0[r] * SCALE_LOG2E);
      if (act1) {
#pragma unroll
        for (int r = 0; r < 16; r++)
          st1[r] = __builtin_amdgcn_exp2f(st1[r] * SCALE_LOG2E);
      }
      int ns = act1 ? 4 : 2;
      bf16x8 paf[4];
#pragma unroll
      for (int s = 0; s < 4; s++) {
        if (s < ns) {
          const f32x16& sv = (s < 2) ? st0 : st1;
          int rb = (s & 1) * 8;
          uint a = cvt_pk(sv[rb + 0], sv[rb + 1]);
          uint b2 = cvt_pk(sv[rb + 2], sv[rb + 3]);
          uint c = cvt_pk(sv[rb + 4], sv[rb + 5]);
          uint d = cvt_pk(sv[rb + 6], sv[rb + 7]);
          asm volatile("v_permlane32_swap_b32 %0, %1" : "+v"(a), "+v"(c));
          asm volatile("v_permlane32_swap_b32 %0, %1" : "+v"(b2), "+v"(d));
          u32x4 u4 = {a, b2, c, d};
          paf[s] = __builtin_bit_cast(bf16x8, u4);
        }
      }
#pragma unroll
      for (int s = 0; s < 4; s++) {
        if (s < ns) {
          lacc = __builtin_amdgcn_mfma_f32_32x32x16_bf16(paf[s], ones, lacc, 0, 0, 0);
#pragma unroll
          for (int dt = 0; dt < 2; dt++) {
            bf16x8 vf = *(const bf16x8*)&Vb[(dt * 32 + q31) * 36 + s * 8 + hi * 4];
            oacc[dt] = __builtin_amdgcn_mfma_f32_32x32x16_bf16(paf[s], vf, oacc[dt], 0, 0, 0);
          }
        }
      }
    }
    if (kb + 1 < T) {
      int b2 = (kb + 1) & 1;
#pragma unroll
      for (int i = 0; i < 2; i++) {
        *(bf16x8*)&Ksh[b2][(i * 32 + sr) * 72 + sc * 8] = kreg[i];
        *(u32x4*)&Vsh[b2][(i * 32 + sr) * 36 + sc * 4] = vreg[i];
      }
    }
  }
  int hh = head % 12, bb = head / 12;
#pragma unroll
  for (int dt = 0; dt < 2; dt++)
#pragma unroll
    for (int r = 0; r < 16; r++) {
      int qr = qstart + (r & 3) + 8 * (r >> 2) + 4 * hi;
      ao[(size_t)(bb * 2048 + qr) * 768 + hh * 64 + dt * 32 + q31] =
          f2bf(oacc[dt][r] / lacc[r]);
    }
}

// ---------- output projection (R8 form): ao[8192,768] @ Wpt + bp -> out fp32.
// grid (64, 6), 128 thr = 2 waves; depth-2 counted-vmcnt dbuf.
__global__ __launch_bounds__(128, 2) void gemm_out(const ushort* __restrict__ A,
                                                   const ushort* __restrict__ Bt,
                                                   const float* __restrict__ bias,
                                                   float* __restrict__ out) {
  __shared__ ushort Ash[2][128 * 32];
  __shared__ ushort Bsh[2][128 * 32];
  int mb = blockIdx.x, nb = blockIdx.y;
  int t = threadIdx.x, w = t >> 6, lane = t & 63, lo = lane & 15, g = lane >> 4;
  const ushort* Ab = A + (size_t)mb * 128 * 768;
  const ushort* Bb = Bt + (size_t)nb * 128 * 768;
  f32x4 acc[4][8];
#pragma unroll
  for (int fi = 0; fi < 4; fi++)
#pragma unroll
    for (int fj = 0; fj < 8; fj++) acc[fi][fj] = (f32x4){0.f, 0.f, 0.f, 0.f};
  uint srow[4], ssc[4];
#pragma unroll
  for (int j = 0; j < 4; j++) {
    uint ci = j * 128 + t;
    srow[j] = ci >> 2;
    ssc[j] = ((ci & 3) ^ swz(ci >> 2)) << 4;
  }

#define OUT_STAGE(tile, bsel)                                                         \
  {                                                                                   \
    int e0 = (tile) * 32;                                                             \
    _Pragma("unroll")                                                                 \
    for (int j = 0; j < 4; j++) {                                                     \
      GLOAD16((const char*)(Ab + (size_t)srow[j] * 768 + e0) + ssc[j],                \
              &Ash[bsel][(j * 128 + w * 64) * 8]);                                    \
      GLOAD16((const char*)(Bb + (size_t)srow[j] * 768 + e0) + ssc[j],                \
              &Bsh[bsel][(j * 128 + w * 64) * 8]);                                    \
    }                                                                                 \
  }

  OUT_STAGE(0, 0);
  OUT_STAGE(1, 1);
  uint rsw = swz(lo) << 4;
  for (int it = 0; it < 24; ++it) {
    if (it < 23) { WAITBAR(8); } else { WAITBAR(0); }
    const ushort* Acur = Ash[it & 1];
    const ushort* Bcur = Bsh[it & 1];
    bf16x8 af[4], bf[8];
#pragma unroll
    for (int fi = 0; fi < 4; fi++) {
      int arow = w * 64 + fi * 16 + lo;
      af[fi] = *(const bf16x8*)((const char*)Acur + arow * 64 + ((g << 4) ^ rsw));
    }
#pragma unroll
    for (int fj = 0; fj < 8; fj++) {
      int brow = fj * 16 + lo;
      bf[fj] = *(const bf16x8*)((const char*)Bcur + brow * 64 + ((g << 4) ^ rsw));
    }
#pragma unroll
    for (int fi = 0; fi < 4; fi++)
#pragma unroll
      for (int fj = 0; fj < 8; fj++)
        acc[fi][fj] = __builtin_amdgcn_mfma_f32_16x16x32_bf16(af[fi], bf[fj], acc[fi][fj], 0, 0, 0);
    if (it < 22) {
      ENDBAR();
      OUT_STAGE(it + 2, it & 1);
    }
  }
#undef OUT_STAGE
#pragma unroll
  for (int fj = 0; fj < 8; fj++) {
    int col = nb * 128 + fj * 16 + lo;
    float bv = bias[col];
#pragma unroll
    for (int fi = 0; fi < 4; fi++)
#pragma unroll
      for (int rr = 0; rr < 4; rr++) {
        int m = mb * 128 + w * 64 + fi * 16 + g * 4 + rr;
        out[(size_t)m * 768 + col] = acc[fi][fj][rr] + bv;
      }
  }
}

extern "C" void kernel_launch(void* const* d_in, const int* in_sizes, int n_in,
                              void* d_out, int out_size, void* d_ws, size_t ws_size,
                              hipStream_t stream) {
  const float* x  = (const float*)d_in[0];
  const float* Wq = (const float*)d_in[1];
  const float* Wk = (const float*)d_in[2];
  const float* Wv = (const float*)d_in[3];
  const float* Wp = (const float*)d_in[4];
  const float* bp = (const float*)d_in[5];
  float* out = (float*)d_out;
  ushort* ws = (ushort*)d_ws;

  ushort* xb  = ws + OFF_XB;
  ushort* wt  = ws + OFF_WT;
  ushort* wpt = ws + OFF_WPT;
  ushort* qkv = ws + OFF_QKV;                          // q, k
  uint*   vt  = (uint*)(ws + OFF_QKV + 2 * 6291456);   // packed-transposed v
  ushort* ao  = ws + OFF_AO;

  prep<<<dim3(3648), 256, 0, stream>>>(x, Wq, Wk, Wv, Wp, xb, wt, wpt);
  gemm_qkv<<<dim3(64, 18), 128, 0, stream>>>(xb, wt, qkv, vt);
  attn_fwd<<<dim3(768), 256, 0, stream>>>(qkv, qkv + 6291456, vt, ao);
  gemm_out<<<dim3(64, 6), 128, 0, stream>>>(ao, wpt, bp, out);
}